// Round 1
// baseline (563.652 us; speedup 1.0000x reference)
//
#include <hip/hip_runtime.h>

// ---- problem dims (fixed) ----
#define TT 2048   // tokens = B*S
#define HH 1024   // hidden
#define FF 4096   // intermediate
#define EE 8      // experts
#define ROWS_CAP 5120  // 4096 token-slots + per-expert pad to 128, rounded up

typedef __bf16 bf16;
typedef bf16 bf16x8 __attribute__((ext_vector_type(8)));
typedef bf16 bf16x4 __attribute__((ext_vector_type(4)));
typedef bf16 bf16x2 __attribute__((ext_vector_type(2)));
typedef float floatx4 __attribute__((ext_vector_type(4)));

// ---- workspace layout (bytes) ----
#define OFF_W1T  ((size_t)0)                       // [E][F][H] bf16 = 67108864
#define OFF_W2T  (OFF_W1T + (size_t)67108864)      // [E][H][F] bf16 = 67108864
#define OFF_XG   (OFF_W2T + (size_t)67108864)      // [ROWS_CAP][H] bf16 = 10485760
#define OFF_H    (OFF_XG  + (size_t)10485760)      // [ROWS_CAP][F] bf16 = 41943040
#define OFF_CNT  (OFF_H   + (size_t)41943040)      // int[8] (256B slot)
#define OFF_OFS  (OFF_CNT + (size_t)256)           // int[8] (256B slot)
#define OFF_TKE  (OFF_OFS + (size_t)256)           // int[T][2]
#define OFF_TKR  (OFF_TKE + (size_t)16384)         // int[T][2]
#define OFF_TKW  (OFF_TKR + (size_t)16384)         // float[T][2]
#define OFF_R2T  (OFF_TKW + (size_t)16384)         // int[ROWS_CAP]
#define OFF_RW   (OFF_R2T + (size_t)20480)         // float[ROWS_CAP]

// async global->LDS, 16B per lane; LDS dest must be wave-uniform base (+lane*16 implicit)
__device__ __forceinline__ void gload16(const bf16* g, bf16* l) {
    __builtin_amdgcn_global_load_lds((const __attribute__((address_space(1))) void*)g,
                                     (__attribute__((address_space(3))) void*)l, 16, 0, 0);
}

// ---- transpose + fp32->bf16 convert: in[e][r][c] fp32 -> out[e][c][r] bf16 ----
__global__ __launch_bounds__(256) void transpose_cvt(const float* __restrict__ in,
                                                     bf16* __restrict__ out,
                                                     int R, int C) {
    __shared__ float tile[32][33];
    const int e  = blockIdx.z;
    const int r0 = blockIdx.y * 32, c0 = blockIdx.x * 32;
    const float* inp = in + (size_t)e * R * C;
    bf16* outp = out + (size_t)e * R * C;
    const int tid = threadIdx.x;
    {
        int r  = tid >> 3;
        int c4 = (tid & 7) << 2;
        floatx4 v = *(const floatx4*)&inp[(size_t)(r0 + r) * C + c0 + c4];
        tile[r][c4 + 0] = v[0]; tile[r][c4 + 1] = v[1];
        tile[r][c4 + 2] = v[2]; tile[r][c4 + 3] = v[3];
    }
    __syncthreads();
    {
        int rp = (tid & 15) << 1;   // row pair in tile (becomes contiguous out cols)
        int cl = tid >> 4;          // 0..15
#pragma unroll
        for (int p = 0; p < 2; ++p) {
            int c = cl + p * 16;
            bf16x2 v;
            v[0] = (bf16)tile[rp][c];
            v[1] = (bf16)tile[rp + 1][c];
            *(bf16x2*)&outp[(size_t)(c0 + c) * R + r0 + rp] = v;
        }
    }
}

// ---- router: fp64-accurate logits, top-2, renormalized weights, rank via atomics ----
__global__ __launch_bounds__(256) void router_kernel(const float* __restrict__ x,
                                                     const float* __restrict__ gw,
                                                     const float* __restrict__ gb,
                                                     int* __restrict__ counts,
                                                     int* __restrict__ tke,
                                                     int* __restrict__ tkr,
                                                     float* __restrict__ tkw) {
    const int wave = blockIdx.x * 4 + (threadIdx.x >> 6);
    const int lane = threadIdx.x & 63;
    const int nw = gridDim.x * 4;
    for (int t = wave; t < TT; t += nw) {
        const float* xr = x + (size_t)t * HH;
        double acc[EE];
#pragma unroll
        for (int e = 0; e < EE; ++e) acc[e] = 0.0;
        for (int h = lane; h < HH; h += 64) {
            double xv = (double)xr[h];
            const float* g = gw + (size_t)h * EE;
            floatx4 g0 = *(const floatx4*)&g[0];
            floatx4 g1 = *(const floatx4*)&g[4];
            acc[0] += xv * (double)g0[0]; acc[1] += xv * (double)g0[1];
            acc[2] += xv * (double)g0[2]; acc[3] += xv * (double)g0[3];
            acc[4] += xv * (double)g1[0]; acc[5] += xv * (double)g1[1];
            acc[6] += xv * (double)g1[2]; acc[7] += xv * (double)g1[3];
        }
#pragma unroll
        for (int e = 0; e < EE; ++e) {
            double v = acc[e];
            for (int s = 32; s > 0; s >>= 1) v += __shfl_xor(v, s, 64);
            acc[e] = v + (double)gb[e];
        }
        if (lane == 0) {
            int i1 = 0; double v1 = acc[0];
            for (int e = 1; e < EE; ++e) if (acc[e] > v1) { v1 = acc[e]; i1 = e; }
            int i2 = -1; double v2 = -1e300;
            for (int e = 0; e < EE; ++e) if (e != i1 && acc[e] > v2) { v2 = acc[e]; i2 = e; }
            double wa = 1.0 / (1.0 + exp(v2 - v1));   // = renormalized softmax of top-2
            double wb = 1.0 - wa;
            int r1 = atomicAdd(&counts[i1], 1);
            int r2 = atomicAdd(&counts[i2], 1);
            tke[t * 2 + 0] = i1; tke[t * 2 + 1] = i2;
            tkr[t * 2 + 0] = r1; tkr[t * 2 + 1] = r2;
            tkw[t * 2 + 0] = (float)wa; tkw[t * 2 + 1] = (float)wb;
        }
    }
}

// ---- exclusive scan of counts padded to 128 ----
__global__ void scan_offsets(const int* __restrict__ counts, int* __restrict__ offs) {
    if (threadIdx.x == 0 && blockIdx.x == 0) {
        int off = 0;
        for (int e = 0; e < EE; ++e) {
            offs[e] = off;
            off += (counts[e] + 127) & ~127;
        }
    }
}

// ---- gather token rows into expert-grouped bf16 matrix ----
__global__ __launch_bounds__(256) void gather_kernel(const float* __restrict__ x,
                                                     const int* __restrict__ tke,
                                                     const int* __restrict__ tkr,
                                                     const float* __restrict__ tkw,
                                                     const int* __restrict__ offs,
                                                     bf16* __restrict__ xg,
                                                     int* __restrict__ r2t,
                                                     float* __restrict__ rw) {
    const int pair = blockIdx.x;       // t*2 + slot
    const int t = pair >> 1;
    const int e = tke[pair];
    const int row = offs[e] + tkr[pair];
    const float* xr = x + (size_t)t * HH;
    bf16* dst = xg + (size_t)row * HH;
    const int tid = threadIdx.x;
    floatx4 v = ((const floatx4*)xr)[tid];
    bf16x4 o;
    o[0] = (bf16)v[0]; o[1] = (bf16)v[1]; o[2] = (bf16)v[2]; o[3] = (bf16)v[3];
    ((bf16x4*)dst)[tid] = o;
    if (tid == 0) { r2t[row] = t; rw[row] = tkw[pair]; }
}

// ---- GEMM1: h = relu(xg @ w1[e] + b1[e]) -> bf16.  A:[rows,1024]  Bt:[E][4096][1024] ----
__global__ __launch_bounds__(256, 2) void gemm1_kernel(const bf16* __restrict__ A,
                                                       const bf16* __restrict__ Bt,
                                                       const float* __restrict__ b1,
                                                       bf16* __restrict__ Hout,
                                                       const int* __restrict__ counts,
                                                       const int* __restrict__ offs) {
    const int e = blockIdx.z, mt = blockIdx.y, nt = blockIdx.x;
    const int cnt = counts[e];
    if (mt * 128 >= cnt) return;
    const int row0 = offs[e] + mt * 128;
    const int K = HH;
    const bf16* Ab = A + (size_t)row0 * K;
    const bf16* Bb = Bt + ((size_t)e * FF + (size_t)nt * 128) * K;

    __shared__ bf16 As[128 * 32];
    __shared__ bf16 Bs[128 * 32];

    const int tid = threadIdx.x;
    const int lane = tid & 63, wave = tid >> 6;
    const int lrow = lane & 15, lq = lane >> 4;
    const int m_w = (wave & 1) << 6, n_w = (wave >> 1) << 6;
    const int swz = (lrow >> 1) & 3;            // xor-swizzle: same for every 16-row subtile
    const unsigned foff = (unsigned)((lq ^ swz) << 3);

    floatx4 acc[4][4];
#pragma unroll
    for (int i = 0; i < 4; ++i)
#pragma unroll
        for (int j = 0; j < 4; ++j) acc[i][j] = (floatx4){0.f, 0.f, 0.f, 0.f};

    const int c0 = tid, c1 = tid + 256;
    const int ar0 = c0 >> 2, ak0 = (c0 & 3) ^ ((ar0 >> 1) & 3);
    const int ar1 = c1 >> 2, ak1 = (c1 & 3) ^ ((ar1 >> 1) & 3);
    const unsigned lds0 = (unsigned)((tid & ~63) << 4);
    const unsigned lds1 = 4096u + lds0;
    const size_t ga0 = (size_t)ar0 * K + ak0 * 8;
    const size_t ga1 = (size_t)ar1 * K + ak1 * 8;

    for (int kt = 0; kt < K / 32; ++kt) {
        const int kb = kt * 32;
        gload16(Ab + ga0 + kb, (bf16*)((char*)As + lds0));
        gload16(Ab + ga1 + kb, (bf16*)((char*)As + lds1));
        gload16(Bb + ga0 + kb, (bf16*)((char*)Bs + lds0));
        gload16(Bb + ga1 + kb, (bf16*)((char*)Bs + lds1));
        asm volatile("s_waitcnt vmcnt(0)" ::: "memory");
        __syncthreads();

        bf16x8 af[4], bfr[4];
#pragma unroll
        for (int i = 0; i < 4; ++i) {
            int m = m_w + i * 16 + lrow;
            af[i] = *(const bf16x8*)&As[(unsigned)m * 32 + foff];
        }
#pragma unroll
        for (int j = 0; j < 4; ++j) {
            int n = n_w + j * 16 + lrow;
            bfr[j] = *(const bf16x8*)&Bs[(unsigned)n * 32 + foff];
        }
#pragma unroll
        for (int i = 0; i < 4; ++i)
#pragma unroll
            for (int j = 0; j < 4; ++j)
                acc[i][j] = __builtin_amdgcn_mfma_f32_16x16x32_bf16(af[i], bfr[j], acc[i][j], 0, 0, 0);
        __syncthreads();
    }

    const float* bias = b1 + (size_t)e * FF + (size_t)nt * 128;
    bf16* Hb = Hout + (size_t)row0 * FF + (size_t)nt * 128;
#pragma unroll
    for (int j = 0; j < 4; ++j) {
        int col = n_w + j * 16 + lrow;
        float bv = bias[col];
#pragma unroll
        for (int i = 0; i < 4; ++i)
#pragma unroll
            for (int r = 0; r < 4; ++r) {
                int mrow = m_w + i * 16 + (lq << 2) + r;       // C/D: col=lane&15, row=quad*4+reg
                float v = acc[i][j][r] + bv;
                Hb[(size_t)mrow * FF + col] = (bf16)(v > 0.f ? v : 0.f);
            }
    }
}

// ---- GEMM2: out[t] += w * (h @ w2[e] + b2[e]); split-K=2, fp32 atomics ----
__global__ __launch_bounds__(256, 2) void gemm2_kernel(const bf16* __restrict__ Hin,
                                                       const bf16* __restrict__ Bt,
                                                       const float* __restrict__ b2,
                                                       float* __restrict__ out,
                                                       const int* __restrict__ counts,
                                                       const int* __restrict__ offs,
                                                       const int* __restrict__ r2t,
                                                       const float* __restrict__ rw) {
    const int e = blockIdx.z >> 1, ks = blockIdx.z & 1;
    const int mt = blockIdx.y, nt = blockIdx.x;
    const int cnt = counts[e];
    if (mt * 128 >= cnt) return;
    const int row0 = offs[e] + mt * 128;
    const int K = FF;
    const bf16* Ab = Hin + (size_t)row0 * K + ks * 2048;
    const bf16* Bb = Bt + ((size_t)e * HH + (size_t)nt * 128) * K + ks * 2048;

    __shared__ bf16 As[128 * 32];
    __shared__ bf16 Bs[128 * 32];

    const int tid = threadIdx.x;
    const int lane = tid & 63, wave = tid >> 6;
    const int lrow = lane & 15, lq = lane >> 4;
    const int m_w = (wave & 1) << 6, n_w = (wave >> 1) << 6;
    const int swz = (lrow >> 1) & 3;
    const unsigned foff = (unsigned)((lq ^ swz) << 3);

    floatx4 acc[4][4];
#pragma unroll
    for (int i = 0; i < 4; ++i)
#pragma unroll
        for (int j = 0; j < 4; ++j) acc[i][j] = (floatx4){0.f, 0.f, 0.f, 0.f};

    const int c0 = tid, c1 = tid + 256;
    const int ar0 = c0 >> 2, ak0 = (c0 & 3) ^ ((ar0 >> 1) & 3);
    const int ar1 = c1 >> 2, ak1 = (c1 & 3) ^ ((ar1 >> 1) & 3);
    const unsigned lds0 = (unsigned)((tid & ~63) << 4);
    const unsigned lds1 = 4096u + lds0;
    const size_t ga0 = (size_t)ar0 * K + ak0 * 8;
    const size_t ga1 = (size_t)ar1 * K + ak1 * 8;

    for (int kt = 0; kt < 64; ++kt) {
        const int kb = kt * 32;
        gload16(Ab + ga0 + kb, (bf16*)((char*)As + lds0));
        gload16(Ab + ga1 + kb, (bf16*)((char*)As + lds1));
        gload16(Bb + ga0 + kb, (bf16*)((char*)Bs + lds0));
        gload16(Bb + ga1 + kb, (bf16*)((char*)Bs + lds1));
        asm volatile("s_waitcnt vmcnt(0)" ::: "memory");
        __syncthreads();

        bf16x8 af[4], bfr[4];
#pragma unroll
        for (int i = 0; i < 4; ++i) {
            int m = m_w + i * 16 + lrow;
            af[i] = *(const bf16x8*)&As[(unsigned)m * 32 + foff];
        }
#pragma unroll
        for (int j = 0; j < 4; ++j) {
            int n = n_w + j * 16 + lrow;
            bfr[j] = *(const bf16x8*)&Bs[(unsigned)n * 32 + foff];
        }
#pragma unroll
        for (int i = 0; i < 4; ++i)
#pragma unroll
            for (int j = 0; j < 4; ++j)
                acc[i][j] = __builtin_amdgcn_mfma_f32_16x16x32_bf16(af[i], bfr[j], acc[i][j], 0, 0, 0);
        __syncthreads();
    }

    const float* bias = b2 + (size_t)e * HH + (size_t)nt * 128;
    const int valid = cnt - mt * 128;
#pragma unroll
    for (int i = 0; i < 4; ++i)
#pragma unroll
        for (int r = 0; r < 4; ++r) {
            int mrow = m_w + i * 16 + (lq << 2) + r;
            if (mrow < valid) {
                int row = row0 + mrow;
                int t = r2t[row];
                float w = rw[row];
                float* orow = out + (size_t)t * HH + (size_t)nt * 128;
#pragma unroll
                for (int j = 0; j < 4; ++j) {
                    int col = n_w + j * 16 + lrow;
                    float v = acc[i][j][r];
                    if (ks == 0) v += bias[col];
                    atomicAdd(&orow[col], w * v);
                }
            }
        }
}

extern "C" void kernel_launch(void* const* d_in, const int* in_sizes, int n_in,
                              void* d_out, int out_size, void* d_ws, size_t ws_size,
                              hipStream_t stream) {
    const float* x  = (const float*)d_in[0];
    const float* gw = (const float*)d_in[1];
    const float* gb = (const float*)d_in[2];
    const float* w1 = (const float*)d_in[3];
    const float* b1 = (const float*)d_in[4];
    const float* w2 = (const float*)d_in[5];
    const float* b2 = (const float*)d_in[6];
    float* out = (float*)d_out;
    char* ws = (char*)d_ws;

    bf16*  w1t  = (bf16*)(ws + OFF_W1T);
    bf16*  w2t  = (bf16*)(ws + OFF_W2T);
    bf16*  xg   = (bf16*)(ws + OFF_XG);
    bf16*  hbuf = (bf16*)(ws + OFF_H);
    int*   cnts = (int*)(ws + OFF_CNT);
    int*   ofs  = (int*)(ws + OFF_OFS);
    int*   tke  = (int*)(ws + OFF_TKE);
    int*   tkr  = (int*)(ws + OFF_TKR);
    float* tkw  = (float*)(ws + OFF_TKW);
    int*   r2t  = (int*)(ws + OFF_R2T);
    float* rwp  = (float*)(ws + OFF_RW);

    hipMemsetAsync(cnts, 0, 256, stream);
    hipMemsetAsync(xg, 0, (size_t)ROWS_CAP * HH * sizeof(bf16), stream);
    hipMemsetAsync(out, 0, (size_t)out_size * sizeof(float), stream);

    transpose_cvt<<<dim3(FF / 32, HH / 32, EE), 256, 0, stream>>>(w1, w1t, HH, FF);
    transpose_cvt<<<dim3(HH / 32, FF / 32, EE), 256, 0, stream>>>(w2, w2t, FF, HH);
    router_kernel<<<128, 256, 0, stream>>>(x, gw, gb, cnts, tke, tkr, tkw);
    scan_offsets<<<1, 64, 0, stream>>>(cnts, ofs);
    gather_kernel<<<TT * 2, 256, 0, stream>>>(x, tke, tkr, tkw, ofs, xg, r2t, rwp);
    gemm1_kernel<<<dim3(FF / 128, 16, EE), 256, 0, stream>>>(xg, w1t, b1, hbuf, cnts, ofs);
    gemm2_kernel<<<dim3(HH / 128, 16, EE * 2), 256, 0, stream>>>(hbuf, w2t, b2, out, cnts, ofs, r2t, rwp);
}

// Round 2
// 532.175 us; speedup vs baseline: 1.0591x; 1.0591x over previous
//
#include <hip/hip_runtime.h>

// ---- problem dims (fixed) ----
#define TT 2048   // tokens = B*S
#define HH 1024   // hidden
#define FF 4096   // intermediate
#define EE 8      // experts
#define ROWS_CAP 5120  // 4096 token-slots + per-expert pad to 128, rounded up
#define KSPLIT2 4      // gemm2 split-K factor

typedef __bf16 bf16;
typedef bf16 bf16x8 __attribute__((ext_vector_type(8)));
typedef bf16 bf16x4 __attribute__((ext_vector_type(4)));
typedef bf16 bf16x2 __attribute__((ext_vector_type(2)));
typedef float floatx4 __attribute__((ext_vector_type(4)));

// ---- workspace layout (bytes) ----
#define OFF_W1T  ((size_t)0)                       // [E][F][H] bf16 = 67108864
#define OFF_W2T  (OFF_W1T + (size_t)67108864)      // [E][H][F] bf16 = 67108864
#define OFF_XG   (OFF_W2T + (size_t)67108864)      // [ROWS_CAP][H] bf16 = 10485760
#define OFF_H    (OFF_XG  + (size_t)10485760)      // [ROWS_CAP][F] bf16 = 41943040
#define OFF_CNT  (OFF_H   + (size_t)41943040)      // int[8] (256B slot)
#define OFF_OFS  (OFF_CNT + (size_t)256)           // int[8] (256B slot)
#define OFF_TKE  (OFF_OFS + (size_t)256)           // int[T][2]
#define OFF_TKR  (OFF_TKE + (size_t)16384)         // int[T][2]
#define OFF_TKW  (OFF_TKR + (size_t)16384)         // float[T][2]
#define OFF_ROW  (OFF_TKW + (size_t)16384)         // int[T][2] row index per (token,slot)
// Y partials [KSPLIT2][ROWS_CAP][HH] bf16 = 41943040 bytes — ALIASES w1t region:
// w1t is dead after gemm1 (stream order: transpose -> gemm1 -> gemm2 -> combine).
#define OFF_Y    OFF_W1T

// async global->LDS, 16B per lane; LDS dest must be wave-uniform base (+lane*16 implicit)
__device__ __forceinline__ void gload16(const bf16* g, bf16* l) {
    __builtin_amdgcn_global_load_lds((const __attribute__((address_space(1))) void*)g,
                                     (__attribute__((address_space(3))) void*)l, 16, 0, 0);
}

// ---- transpose + fp32->bf16 convert: in[e][r][c] fp32 -> out[e][c][r] bf16 ----
// 64x64 tiles; writes are bf16x8 (16B) -> 128B contiguous per output column.
__global__ __launch_bounds__(256) void transpose_cvt(const float* __restrict__ in,
                                                     bf16* __restrict__ out,
                                                     int R, int C) {
    __shared__ float tile[64][67];   // pad 67: 2-way max bank aliasing on both phases
    const int e  = blockIdx.z;
    const int r0 = blockIdx.y * 64, c0 = blockIdx.x * 64;
    const float* inp = in + (size_t)e * R * C;
    bf16* outp = out + (size_t)e * R * C;
    const int t = threadIdx.x;
    {
        const int lr = t >> 4;            // 0..15
        const int lc = (t & 15) << 2;     // 0..60 step 4 (16 lanes * 16B = 256B/row)
#pragma unroll
        for (int i = 0; i < 4; ++i) {
            int r = lr + i * 16;
            floatx4 v = *(const floatx4*)&inp[(size_t)(r0 + r) * C + c0 + lc];
            tile[r][lc + 0] = v[0]; tile[r][lc + 1] = v[1];
            tile[r][lc + 2] = v[2]; tile[r][lc + 3] = v[3];
        }
    }
    __syncthreads();
    {
        const int c  = t >> 3;            // 0..31
        const int rq = (t & 7) << 3;      // 0..56 step 8
#pragma unroll
        for (int i = 0; i < 2; ++i) {
            int cc = c + i * 32;
            bf16x8 o;
#pragma unroll
            for (int k = 0; k < 8; ++k) o[k] = (bf16)tile[rq + k][cc];
            *(bf16x8*)&outp[(size_t)(c0 + cc) * R + r0 + rq] = o;
        }
    }
}

// ---- router: fp64-accurate logits, top-2, renormalized weights, rank via atomics ----
__global__ __launch_bounds__(256) void router_kernel(const float* __restrict__ x,
                                                     const float* __restrict__ gw,
                                                     const float* __restrict__ gb,
                                                     int* __restrict__ counts,
                                                     int* __restrict__ tke,
                                                     int* __restrict__ tkr,
                                                     float* __restrict__ tkw) {
    const int wave = blockIdx.x * 4 + (threadIdx.x >> 6);
    const int lane = threadIdx.x & 63;
    const int nw = gridDim.x * 4;
    for (int t = wave; t < TT; t += nw) {
        const float* xr = x + (size_t)t * HH;
        double acc[EE];
#pragma unroll
        for (int e = 0; e < EE; ++e) acc[e] = 0.0;
        for (int h = lane; h < HH; h += 64) {
            double xv = (double)xr[h];
            const float* g = gw + (size_t)h * EE;
            floatx4 g0 = *(const floatx4*)&g[0];
            floatx4 g1 = *(const floatx4*)&g[4];
            acc[0] += xv * (double)g0[0]; acc[1] += xv * (double)g0[1];
            acc[2] += xv * (double)g0[2]; acc[3] += xv * (double)g0[3];
            acc[4] += xv * (double)g1[0]; acc[5] += xv * (double)g1[1];
            acc[6] += xv * (double)g1[2]; acc[7] += xv * (double)g1[3];
        }
#pragma unroll
        for (int e = 0; e < EE; ++e) {
            double v = acc[e];
            for (int s = 32; s > 0; s >>= 1) v += __shfl_xor(v, s, 64);
            acc[e] = v + (double)gb[e];
        }
        if (lane == 0) {
            int i1 = 0; double v1 = acc[0];
            for (int e = 1; e < EE; ++e) if (acc[e] > v1) { v1 = acc[e]; i1 = e; }
            int i2 = -1; double v2 = -1e300;
            for (int e = 0; e < EE; ++e) if (e != i1 && acc[e] > v2) { v2 = acc[e]; i2 = e; }
            double wa = 1.0 / (1.0 + exp(v2 - v1));   // = renormalized softmax of top-2
            double wb = 1.0 - wa;
            int r1 = atomicAdd(&counts[i1], 1);
            int r2 = atomicAdd(&counts[i2], 1);
            tke[t * 2 + 0] = i1; tke[t * 2 + 1] = i2;
            tkr[t * 2 + 0] = r1; tkr[t * 2 + 1] = r2;
            tkw[t * 2 + 0] = (float)wa; tkw[t * 2 + 1] = (float)wb;
        }
    }
}

// ---- exclusive scan of counts padded to 128 ----
__global__ void scan_offsets(const int* __restrict__ counts, int* __restrict__ offs) {
    if (threadIdx.x == 0 && blockIdx.x == 0) {
        int off = 0;
        for (int e = 0; e < EE; ++e) {
            offs[e] = off;
            off += (counts[e] + 127) & ~127;
        }
    }
}

// ---- gather token rows into expert-grouped bf16 matrix; record row per (token,slot) ----
__global__ __launch_bounds__(256) void gather_kernel(const float* __restrict__ x,
                                                     const int* __restrict__ tke,
                                                     const int* __restrict__ tkr,
                                                     const int* __restrict__ offs,
                                                     bf16* __restrict__ xg,
                                                     int* __restrict__ rowOf) {
    const int pair = blockIdx.x;       // t*2 + slot
    const int t = pair >> 1;
    const int e = tke[pair];
    const int row = offs[e] + tkr[pair];
    const float* xr = x + (size_t)t * HH;
    bf16* dst = xg + (size_t)row * HH;
    const int tid = threadIdx.x;
    floatx4 v = ((const floatx4*)xr)[tid];
    bf16x4 o;
    o[0] = (bf16)v[0]; o[1] = (bf16)v[1]; o[2] = (bf16)v[2]; o[3] = (bf16)v[3];
    ((bf16x4*)dst)[tid] = o;
    if (tid == 0) rowOf[pair] = row;
}

// ---- GEMM1: h = relu(xg @ w1[e] + b1[e]) -> bf16.  A:[rows,1024]  Bt:[E][4096][1024] ----
__global__ __launch_bounds__(256, 2) void gemm1_kernel(const bf16* __restrict__ A,
                                                       const bf16* __restrict__ Bt,
                                                       const float* __restrict__ b1,
                                                       bf16* __restrict__ Hout,
                                                       const int* __restrict__ counts,
                                                       const int* __restrict__ offs) {
    const int e = blockIdx.z, mt = blockIdx.y, nt = blockIdx.x;
    const int cnt = counts[e];
    if (mt * 128 >= cnt) return;
    const int row0 = offs[e] + mt * 128;
    const int K = HH;
    const bf16* Ab = A + (size_t)row0 * K;
    const bf16* Bb = Bt + ((size_t)e * FF + (size_t)nt * 128) * K;

    __shared__ bf16 As[128 * 32];
    __shared__ bf16 Bs[128 * 32];

    const int tid = threadIdx.x;
    const int lane = tid & 63, wave = tid >> 6;
    const int lrow = lane & 15, lq = lane >> 4;
    const int m_w = (wave & 1) << 6, n_w = (wave >> 1) << 6;
    const int swz = (lrow >> 1) & 3;
    const unsigned foff = (unsigned)((lq ^ swz) << 3);

    floatx4 acc[4][4];
#pragma unroll
    for (int i = 0; i < 4; ++i)
#pragma unroll
        for (int j = 0; j < 4; ++j) acc[i][j] = (floatx4){0.f, 0.f, 0.f, 0.f};

    const int c0 = tid, c1 = tid + 256;
    const int ar0 = c0 >> 2, ak0 = (c0 & 3) ^ ((ar0 >> 1) & 3);
    const int ar1 = c1 >> 2, ak1 = (c1 & 3) ^ ((ar1 >> 1) & 3);
    const unsigned lds0 = (unsigned)((tid & ~63) << 4);
    const unsigned lds1 = 4096u + lds0;
    const size_t ga0 = (size_t)ar0 * K + ak0 * 8;
    const size_t ga1 = (size_t)ar1 * K + ak1 * 8;

    for (int kt = 0; kt < K / 32; ++kt) {
        const int kb = kt * 32;
        gload16(Ab + ga0 + kb, (bf16*)((char*)As + lds0));
        gload16(Ab + ga1 + kb, (bf16*)((char*)As + lds1));
        gload16(Bb + ga0 + kb, (bf16*)((char*)Bs + lds0));
        gload16(Bb + ga1 + kb, (bf16*)((char*)Bs + lds1));
        asm volatile("s_waitcnt vmcnt(0)" ::: "memory");
        __syncthreads();

        bf16x8 af[4], bfr[4];
#pragma unroll
        for (int i = 0; i < 4; ++i) {
            int m = m_w + i * 16 + lrow;
            af[i] = *(const bf16x8*)&As[(unsigned)m * 32 + foff];
        }
#pragma unroll
        for (int j = 0; j < 4; ++j) {
            int n = n_w + j * 16 + lrow;
            bfr[j] = *(const bf16x8*)&Bs[(unsigned)n * 32 + foff];
        }
#pragma unroll
        for (int i = 0; i < 4; ++i)
#pragma unroll
            for (int j = 0; j < 4; ++j)
                acc[i][j] = __builtin_amdgcn_mfma_f32_16x16x32_bf16(af[i], bfr[j], acc[i][j], 0, 0, 0);
        __syncthreads();
    }

    const float* bias = b1 + (size_t)e * FF + (size_t)nt * 128;
    bf16* Hb = Hout + (size_t)row0 * FF + (size_t)nt * 128;
#pragma unroll
    for (int j = 0; j < 4; ++j) {
        int col = n_w + j * 16 + lrow;
        float bv = bias[col];
#pragma unroll
        for (int i = 0; i < 4; ++i)
#pragma unroll
            for (int r = 0; r < 4; ++r) {
                int mrow = m_w + i * 16 + (lq << 2) + r;       // C/D: col=lane&15, row=quad*4+reg
                float v = acc[i][j][r] + bv;
                Hb[(size_t)mrow * FF + col] = (bf16)(v > 0.f ? v : 0.f);
            }
    }
}

// ---- GEMM2: y[ks][row] = (h[:,ksK:(ks+1)K] @ w2[e][:,ksK:...]) (+b2 at ks==0), bf16 out, NO atomics ----
__global__ __launch_bounds__(256, 2) void gemm2_kernel(const bf16* __restrict__ Hin,
                                                       const bf16* __restrict__ Bt,
                                                       const float* __restrict__ b2,
                                                       bf16* __restrict__ Y,
                                                       const int* __restrict__ counts,
                                                       const int* __restrict__ offs) {
    const int e = blockIdx.z >> 2, ks = blockIdx.z & 3;
    const int mt = blockIdx.y, nt = blockIdx.x;
    const int cnt = counts[e];
    if (mt * 128 >= cnt) return;
    const int row0 = offs[e] + mt * 128;
    const int K = FF;                      // full-K row stride
    const int KC = FF / KSPLIT2;           // 1024 per split
    const bf16* Ab = Hin + (size_t)row0 * K + ks * KC;
    const bf16* Bb = Bt + ((size_t)e * HH + (size_t)nt * 128) * K + ks * KC;

    __shared__ bf16 As[128 * 32];
    __shared__ bf16 Bs[128 * 32];

    const int tid = threadIdx.x;
    const int lane = tid & 63, wave = tid >> 6;
    const int lrow = lane & 15, lq = lane >> 4;
    const int m_w = (wave & 1) << 6, n_w = (wave >> 1) << 6;
    const int swz = (lrow >> 1) & 3;
    const unsigned foff = (unsigned)((lq ^ swz) << 3);

    floatx4 acc[4][4];
#pragma unroll
    for (int i = 0; i < 4; ++i)
#pragma unroll
        for (int j = 0; j < 4; ++j) acc[i][j] = (floatx4){0.f, 0.f, 0.f, 0.f};

    const int c0 = tid, c1 = tid + 256;
    const int ar0 = c0 >> 2, ak0 = (c0 & 3) ^ ((ar0 >> 1) & 3);
    const int ar1 = c1 >> 2, ak1 = (c1 & 3) ^ ((ar1 >> 1) & 3);
    const unsigned lds0 = (unsigned)((tid & ~63) << 4);
    const unsigned lds1 = 4096u + lds0;
    const size_t ga0 = (size_t)ar0 * K + ak0 * 8;
    const size_t ga1 = (size_t)ar1 * K + ak1 * 8;

    for (int kt = 0; kt < KC / 32; ++kt) {
        const int kb = kt * 32;
        gload16(Ab + ga0 + kb, (bf16*)((char*)As + lds0));
        gload16(Ab + ga1 + kb, (bf16*)((char*)As + lds1));
        gload16(Bb + ga0 + kb, (bf16*)((char*)Bs + lds0));
        gload16(Bb + ga1 + kb, (bf16*)((char*)Bs + lds1));
        asm volatile("s_waitcnt vmcnt(0)" ::: "memory");
        __syncthreads();

        bf16x8 af[4], bfr[4];
#pragma unroll
        for (int i = 0; i < 4; ++i) {
            int m = m_w + i * 16 + lrow;
            af[i] = *(const bf16x8*)&As[(unsigned)m * 32 + foff];
        }
#pragma unroll
        for (int j = 0; j < 4; ++j) {
            int n = n_w + j * 16 + lrow;
            bfr[j] = *(const bf16x8*)&Bs[(unsigned)n * 32 + foff];
        }
#pragma unroll
        for (int i = 0; i < 4; ++i)
#pragma unroll
            for (int j = 0; j < 4; ++j)
                acc[i][j] = __builtin_amdgcn_mfma_f32_16x16x32_bf16(af[i], bfr[j], acc[i][j], 0, 0, 0);
        __syncthreads();
    }

    const float* bias = b2 + (size_t)e * HH + (size_t)nt * 128;
    bf16* Yb = Y + ((size_t)ks * ROWS_CAP + row0) * HH + (size_t)nt * 128;
#pragma unroll
    for (int j = 0; j < 4; ++j) {
        int col = n_w + j * 16 + lrow;
        float bv = (ks == 0) ? bias[col] : 0.f;
#pragma unroll
        for (int i = 0; i < 4; ++i)
#pragma unroll
            for (int r = 0; r < 4; ++r) {
                int mrow = m_w + i * 16 + (lq << 2) + r;
                Yb[(size_t)mrow * HH + col] = (bf16)(acc[i][j][r] + bv);
            }
    }
}

// ---- combine: out[t] = sum_slot w_slot * sum_ks y[ks][row_slot] ----
__global__ __launch_bounds__(256) void combine_kernel(const bf16* __restrict__ Y,
                                                      const int* __restrict__ rowOf,
                                                      const float* __restrict__ tkw,
                                                      float* __restrict__ out) {
    const int t = blockIdx.x;
    const int tid = threadIdx.x;
    const int ra = rowOf[t * 2 + 0], rb = rowOf[t * 2 + 1];
    const float wa = tkw[t * 2 + 0], wb = tkw[t * 2 + 1];
    const int c = tid * 4;
    float acc[4] = {0.f, 0.f, 0.f, 0.f};
#pragma unroll
    for (int ks = 0; ks < KSPLIT2; ++ks) {
        bf16x4 a = *(const bf16x4*)&Y[((size_t)ks * ROWS_CAP + ra) * HH + c];
        bf16x4 b = *(const bf16x4*)&Y[((size_t)ks * ROWS_CAP + rb) * HH + c];
#pragma unroll
        for (int k = 0; k < 4; ++k) acc[k] += wa * (float)a[k] + wb * (float)b[k];
    }
    floatx4 o; o[0] = acc[0]; o[1] = acc[1]; o[2] = acc[2]; o[3] = acc[3];
    *(floatx4*)&out[(size_t)t * HH + c] = o;
}

extern "C" void kernel_launch(void* const* d_in, const int* in_sizes, int n_in,
                              void* d_out, int out_size, void* d_ws, size_t ws_size,
                              hipStream_t stream) {
    const float* x  = (const float*)d_in[0];
    const float* gw = (const float*)d_in[1];
    const float* gb = (const float*)d_in[2];
    const float* w1 = (const float*)d_in[3];
    const float* b1 = (const float*)d_in[4];
    const float* w2 = (const float*)d_in[5];
    const float* b2 = (const float*)d_in[6];
    float* out = (float*)d_out;
    char* ws = (char*)d_ws;

    bf16*  w1t  = (bf16*)(ws + OFF_W1T);
    bf16*  w2t  = (bf16*)(ws + OFF_W2T);
    bf16*  xg   = (bf16*)(ws + OFF_XG);
    bf16*  hbuf = (bf16*)(ws + OFF_H);
    bf16*  ybuf = (bf16*)(ws + OFF_Y);     // aliases w1t (dead after gemm1)
    int*   cnts = (int*)(ws + OFF_CNT);
    int*   ofs  = (int*)(ws + OFF_OFS);
    int*   tke  = (int*)(ws + OFF_TKE);
    int*   tkr  = (int*)(ws + OFF_TKR);
    float* tkw  = (float*)(ws + OFF_TKW);
    int*   rowOf= (int*)(ws + OFF_ROW);

    hipMemsetAsync(cnts, 0, 256, stream);
    hipMemsetAsync(xg, 0, (size_t)ROWS_CAP * HH * sizeof(bf16), stream);

    transpose_cvt<<<dim3(FF / 64, HH / 64, EE), 256, 0, stream>>>(w1, w1t, HH, FF);
    transpose_cvt<<<dim3(HH / 64, FF / 64, EE), 256, 0, stream>>>(w2, w2t, FF, HH);
    router_kernel<<<128, 256, 0, stream>>>(x, gw, gb, cnts, tke, tkr, tkw);
    scan_offsets<<<1, 64, 0, stream>>>(cnts, ofs);
    gather_kernel<<<TT * 2, 256, 0, stream>>>(x, tke, tkr, ofs, xg, rowOf);
    gemm1_kernel<<<dim3(FF / 128, 16, EE), 256, 0, stream>>>(xg, w1t, b1, hbuf, cnts, ofs);
    gemm2_kernel<<<dim3(HH / 128, 16, EE * KSPLIT2), 256, 0, stream>>>(hbuf, w2t, b2, ybuf, cnts, ofs);
    combine_kernel<<<TT, 256, 0, stream>>>(ybuf, rowOf, tkw, out);
}

// Round 3
// 512.543 us; speedup vs baseline: 1.0997x; 1.0383x over previous
//
#include <hip/hip_runtime.h>

// ---- problem dims (fixed) ----
#define TT 2048   // tokens = B*S
#define HH 1024   // hidden
#define FF 4096   // intermediate
#define EE 8      // experts
#define ROWS_CAP 5120  // 4096 token-slots + per-expert pad to 128, rounded up
#define KSPLIT2 4      // gemm2 split-K factor

typedef __bf16 bf16;
typedef bf16 bf16x8 __attribute__((ext_vector_type(8)));
typedef bf16 bf16x4 __attribute__((ext_vector_type(4)));
typedef bf16 bf16x2 __attribute__((ext_vector_type(2)));
typedef float floatx4 __attribute__((ext_vector_type(4)));

// ---- workspace layout (bytes) ----
#define OFF_W1T  ((size_t)0)                       // [E][F][H] bf16 = 67108864
#define OFF_W2T  (OFF_W1T + (size_t)67108864)      // [E][H][F] bf16 = 67108864
#define OFF_XG   (OFF_W2T + (size_t)67108864)      // [ROWS_CAP][H] bf16 = 10485760
#define OFF_H    (OFF_XG  + (size_t)10485760)      // [ROWS_CAP][F] bf16 = 41943040
#define OFF_CNT  (OFF_H   + (size_t)41943040)      // int[8] (256B slot)
#define OFF_OFS  (OFF_CNT + (size_t)256)           // int[8] (256B slot)
#define OFF_TKE  (OFF_OFS + (size_t)256)           // int[T][2]
#define OFF_TKR  (OFF_TKE + (size_t)16384)         // int[T][2]
#define OFF_TKW  (OFF_TKR + (size_t)16384)         // float[T][2]
#define OFF_ROW  (OFF_TKW + (size_t)16384)         // int[T][2] row index per (token,slot)
// Y partials [KSPLIT2][ROWS_CAP][HH] bf16 = 41943040 bytes — ALIASES w1t region:
// w1t is dead after gemm1 (stream order: transpose -> gemm1 -> gemm2 -> combine).
#define OFF_Y    OFF_W1T

// async global->LDS, 16B per lane; LDS dest must be wave-uniform base (+lane*16 implicit)
__device__ __forceinline__ void gload16(const bf16* g, bf16* l) {
    __builtin_amdgcn_global_load_lds((const __attribute__((address_space(1))) void*)g,
                                     (__attribute__((address_space(3))) void*)l, 16, 0, 0);
}

// ---- transpose + fp32->bf16 convert: in[e][r][c] fp32 -> out[e][c][r] bf16 ----
// NT loads: fp32 input is read-once — keep L3 free so the bf16 weight WRITES stay
// resident in Infinity Cache for the GEMMs that follow.
__global__ __launch_bounds__(256) void transpose_cvt(const float* __restrict__ in,
                                                     bf16* __restrict__ out,
                                                     int R, int C) {
    __shared__ float tile[64][67];
    const int e  = blockIdx.z;
    const int r0 = blockIdx.y * 64, c0 = blockIdx.x * 64;
    const float* inp = in + (size_t)e * R * C;
    bf16* outp = out + (size_t)e * R * C;
    const int t = threadIdx.x;
    {
        const int lr = t >> 4;            // 0..15
        const int lc = (t & 15) << 2;     // 0..60 step 4
#pragma unroll
        for (int i = 0; i < 4; ++i) {
            int r = lr + i * 16;
            floatx4 v = __builtin_nontemporal_load(
                (const floatx4*)&inp[(size_t)(r0 + r) * C + c0 + lc]);
            tile[r][lc + 0] = v[0]; tile[r][lc + 1] = v[1];
            tile[r][lc + 2] = v[2]; tile[r][lc + 3] = v[3];
        }
    }
    __syncthreads();
    {
        const int c  = t >> 3;            // 0..31
        const int rq = (t & 7) << 3;      // 0..56 step 8
#pragma unroll
        for (int i = 0; i < 2; ++i) {
            int cc = c + i * 32;
            bf16x8 o;
#pragma unroll
            for (int k = 0; k < 8; ++k) o[k] = (bf16)tile[rq + k][cc];
            *(bf16x8*)&outp[(size_t)(c0 + cc) * R + r0 + rq] = o;
        }
    }
}

// ---- router: fp64-accurate logits, top-2, renormalized weights, rank via atomics ----
__global__ __launch_bounds__(256) void router_kernel(const float* __restrict__ x,
                                                     const float* __restrict__ gw,
                                                     const float* __restrict__ gb,
                                                     int* __restrict__ counts,
                                                     int* __restrict__ tke,
                                                     int* __restrict__ tkr,
                                                     float* __restrict__ tkw) {
    const int wave = blockIdx.x * 4 + (threadIdx.x >> 6);
    const int lane = threadIdx.x & 63;
    const int nw = gridDim.x * 4;
    for (int t = wave; t < TT; t += nw) {
        const float* xr = x + (size_t)t * HH;
        double acc[EE];
#pragma unroll
        for (int e = 0; e < EE; ++e) acc[e] = 0.0;
        for (int h = lane; h < HH; h += 64) {
            double xv = (double)xr[h];
            const float* g = gw + (size_t)h * EE;
            floatx4 g0 = *(const floatx4*)&g[0];
            floatx4 g1 = *(const floatx4*)&g[4];
            acc[0] += xv * (double)g0[0]; acc[1] += xv * (double)g0[1];
            acc[2] += xv * (double)g0[2]; acc[3] += xv * (double)g0[3];
            acc[4] += xv * (double)g1[0]; acc[5] += xv * (double)g1[1];
            acc[6] += xv * (double)g1[2]; acc[7] += xv * (double)g1[3];
        }
#pragma unroll
        for (int e = 0; e < EE; ++e) {
            double v = acc[e];
            for (int s = 32; s > 0; s >>= 1) v += __shfl_xor(v, s, 64);
            acc[e] = v + (double)gb[e];
        }
        if (lane == 0) {
            int i1 = 0; double v1 = acc[0];
            for (int e = 1; e < EE; ++e) if (acc[e] > v1) { v1 = acc[e]; i1 = e; }
            int i2 = -1; double v2 = -1e300;
            for (int e = 0; e < EE; ++e) if (e != i1 && acc[e] > v2) { v2 = acc[e]; i2 = e; }
            double wa = 1.0 / (1.0 + exp(v2 - v1));   // = renormalized softmax of top-2
            double wb = 1.0 - wa;
            int r1 = atomicAdd(&counts[i1], 1);
            int r2 = atomicAdd(&counts[i2], 1);
            tke[t * 2 + 0] = i1; tke[t * 2 + 1] = i2;
            tkr[t * 2 + 0] = r1; tkr[t * 2 + 1] = r2;
            tkw[t * 2 + 0] = (float)wa; tkw[t * 2 + 1] = (float)wb;
        }
    }
}

// ---- exclusive scan of counts padded to 128 ----
__global__ void scan_offsets(const int* __restrict__ counts, int* __restrict__ offs) {
    if (threadIdx.x == 0 && blockIdx.x == 0) {
        int off = 0;
        for (int e = 0; e < EE; ++e) {
            offs[e] = off;
            off += (counts[e] + 127) & ~127;
        }
    }
}

// ---- gather token rows into expert-grouped bf16 matrix; record row per (token,slot) ----
__global__ __launch_bounds__(256) void gather_kernel(const float* __restrict__ x,
                                                     const int* __restrict__ tke,
                                                     const int* __restrict__ tkr,
                                                     const int* __restrict__ offs,
                                                     bf16* __restrict__ xg,
                                                     int* __restrict__ rowOf) {
    const int pair = blockIdx.x;       // t*2 + slot
    const int t = pair >> 1;
    const int e = tke[pair];
    const int row = offs[e] + tkr[pair];
    const float* xr = x + (size_t)t * HH;
    bf16* dst = xg + (size_t)row * HH;
    const int tid = threadIdx.x;
    floatx4 v = ((const floatx4*)xr)[tid];
    bf16x4 o;
    o[0] = (bf16)v[0]; o[1] = (bf16)v[1]; o[2] = (bf16)v[2]; o[3] = (bf16)v[3];
    ((bf16x4*)dst)[tid] = o;
    if (tid == 0) rowOf[pair] = row;
}

// ---- GEMM1: h = relu(xg @ w1[e] + b1[e]) -> bf16. Double-buffered LDS, vmcnt(4). ----
__global__ __launch_bounds__(256, 2) void gemm1_kernel(const bf16* __restrict__ A,
                                                       const bf16* __restrict__ Bt,
                                                       const float* __restrict__ b1,
                                                       bf16* __restrict__ Hout,
                                                       const int* __restrict__ counts,
                                                       const int* __restrict__ offs) {
    const int e = blockIdx.z, mt = blockIdx.y, nt = blockIdx.x;
    const int cnt = counts[e];
    if (mt * 128 >= cnt) return;
    const int row0 = offs[e] + mt * 128;
    const int K = HH;
    const int NK = K / 32;
    const bf16* Ab = A + (size_t)row0 * K;
    const bf16* Bb = Bt + ((size_t)e * FF + (size_t)nt * 128) * K;

    __shared__ bf16 As[2][128 * 32];
    __shared__ bf16 Bs[2][128 * 32];

    const int tid = threadIdx.x;
    const int lane = tid & 63, wave = tid >> 6;
    const int lrow = lane & 15, lq = lane >> 4;
    const int m_w = (wave & 1) << 6, n_w = (wave >> 1) << 6;
    const int swz = (lrow >> 1) & 3;
    const unsigned foff = (unsigned)((lq ^ swz) << 3);

    floatx4 acc[4][4];
#pragma unroll
    for (int i = 0; i < 4; ++i)
#pragma unroll
        for (int j = 0; j < 4; ++j) acc[i][j] = (floatx4){0.f, 0.f, 0.f, 0.f};

    const int c0 = tid, c1 = tid + 256;
    const int ar0 = c0 >> 2, ak0 = (c0 & 3) ^ ((ar0 >> 1) & 3);
    const int ar1 = c1 >> 2, ak1 = (c1 & 3) ^ ((ar1 >> 1) & 3);
    const unsigned lds0 = (unsigned)((tid & ~63) << 4);
    const unsigned lds1 = 4096u + lds0;
    const size_t ga0 = (size_t)ar0 * K + ak0 * 8;
    const size_t ga1 = (size_t)ar1 * K + ak1 * 8;

    // prologue: stage tile 0 into buffer 0
    gload16(Ab + ga0, (bf16*)((char*)As[0] + lds0));
    gload16(Ab + ga1, (bf16*)((char*)As[0] + lds1));
    gload16(Bb + ga0, (bf16*)((char*)Bs[0] + lds0));
    gload16(Bb + ga1, (bf16*)((char*)Bs[0] + lds1));

    for (int kt = 0; kt < NK; ++kt) {
        __syncthreads();   // all waves finished computing on the buffer we overwrite next
        const int kn = (kt + 1 < NK) ? kt + 1 : 0;   // wrap: keeps vmcnt uniform
        const int nb = (kt + 1) & 1;
        const int kb = kn * 32;
        gload16(Ab + ga0 + kb, (bf16*)((char*)As[nb] + lds0));
        gload16(Ab + ga1 + kb, (bf16*)((char*)As[nb] + lds1));
        gload16(Bb + ga0 + kb, (bf16*)((char*)Bs[nb] + lds0));
        gload16(Bb + ga1 + kb, (bf16*)((char*)Bs[nb] + lds1));
        asm volatile("s_waitcnt vmcnt(4)" ::: "memory");  // my 4 loads for tile kt landed
        __syncthreads();                                  // everyone's tile-kt loads landed
        const int cb = kt & 1;

        bf16x8 af[4], bfr[4];
#pragma unroll
        for (int i = 0; i < 4; ++i) {
            int m = m_w + i * 16 + lrow;
            af[i] = *(const bf16x8*)&As[cb][(unsigned)m * 32 + foff];
        }
#pragma unroll
        for (int j = 0; j < 4; ++j) {
            int n = n_w + j * 16 + lrow;
            bfr[j] = *(const bf16x8*)&Bs[cb][(unsigned)n * 32 + foff];
        }
#pragma unroll
        for (int i = 0; i < 4; ++i)
#pragma unroll
            for (int j = 0; j < 4; ++j)
                acc[i][j] = __builtin_amdgcn_mfma_f32_16x16x32_bf16(af[i], bfr[j], acc[i][j], 0, 0, 0);
    }
    asm volatile("s_waitcnt vmcnt(0)" ::: "memory");  // drain stray wrap loads before endpgm

    const float* bias = b1 + (size_t)e * FF + (size_t)nt * 128;
    bf16* Hb = Hout + (size_t)row0 * FF + (size_t)nt * 128;
#pragma unroll
    for (int j = 0; j < 4; ++j) {
        int col = n_w + j * 16 + lrow;
        float bv = bias[col];
#pragma unroll
        for (int i = 0; i < 4; ++i)
#pragma unroll
            for (int r = 0; r < 4; ++r) {
                int mrow = m_w + i * 16 + (lq << 2) + r;       // C/D: col=lane&15, row=quad*4+reg
                float v = acc[i][j][r] + bv;
                Hb[(size_t)mrow * FF + col] = (bf16)(v > 0.f ? v : 0.f);
            }
    }
}

// ---- GEMM2: y[ks][row] = h-slice @ w2-slice (+b2 at ks==0), bf16 NT stores, dbuf LDS ----
__global__ __launch_bounds__(256, 2) void gemm2_kernel(const bf16* __restrict__ Hin,
                                                       const bf16* __restrict__ Bt,
                                                       const float* __restrict__ b2,
                                                       bf16* __restrict__ Y,
                                                       const int* __restrict__ counts,
                                                       const int* __restrict__ offs) {
    const int e = blockIdx.z >> 2, ks = blockIdx.z & 3;
    const int mt = blockIdx.y, nt = blockIdx.x;
    const int cnt = counts[e];
    if (mt * 128 >= cnt) return;
    const int row0 = offs[e] + mt * 128;
    const int K = FF;                      // full-K row stride
    const int KC = FF / KSPLIT2;           // 1024 per split
    const int NK = KC / 32;
    const bf16* Ab = Hin + (size_t)row0 * K + ks * KC;
    const bf16* Bb = Bt + ((size_t)e * HH + (size_t)nt * 128) * K + ks * KC;

    __shared__ bf16 As[2][128 * 32];
    __shared__ bf16 Bs[2][128 * 32];

    const int tid = threadIdx.x;
    const int lane = tid & 63, wave = tid >> 6;
    const int lrow = lane & 15, lq = lane >> 4;
    const int m_w = (wave & 1) << 6, n_w = (wave >> 1) << 6;
    const int swz = (lrow >> 1) & 3;
    const unsigned foff = (unsigned)((lq ^ swz) << 3);

    floatx4 acc[4][4];
#pragma unroll
    for (int i = 0; i < 4; ++i)
#pragma unroll
        for (int j = 0; j < 4; ++j) acc[i][j] = (floatx4){0.f, 0.f, 0.f, 0.f};

    const int c0 = tid, c1 = tid + 256;
    const int ar0 = c0 >> 2, ak0 = (c0 & 3) ^ ((ar0 >> 1) & 3);
    const int ar1 = c1 >> 2, ak1 = (c1 & 3) ^ ((ar1 >> 1) & 3);
    const unsigned lds0 = (unsigned)((tid & ~63) << 4);
    const unsigned lds1 = 4096u + lds0;
    const size_t ga0 = (size_t)ar0 * K + ak0 * 8;
    const size_t ga1 = (size_t)ar1 * K + ak1 * 8;

    gload16(Ab + ga0, (bf16*)((char*)As[0] + lds0));
    gload16(Ab + ga1, (bf16*)((char*)As[0] + lds1));
    gload16(Bb + ga0, (bf16*)((char*)Bs[0] + lds0));
    gload16(Bb + ga1, (bf16*)((char*)Bs[0] + lds1));

    for (int kt = 0; kt < NK; ++kt) {
        __syncthreads();
        const int kn = (kt + 1 < NK) ? kt + 1 : 0;
        const int nb = (kt + 1) & 1;
        const int kb = kn * 32;
        gload16(Ab + ga0 + kb, (bf16*)((char*)As[nb] + lds0));
        gload16(Ab + ga1 + kb, (bf16*)((char*)As[nb] + lds1));
        gload16(Bb + ga0 + kb, (bf16*)((char*)Bs[nb] + lds0));
        gload16(Bb + ga1 + kb, (bf16*)((char*)Bs[nb] + lds1));
        asm volatile("s_waitcnt vmcnt(4)" ::: "memory");
        __syncthreads();
        const int cb = kt & 1;

        bf16x8 af[4], bfr[4];
#pragma unroll
        for (int i = 0; i < 4; ++i) {
            int m = m_w + i * 16 + lrow;
            af[i] = *(const bf16x8*)&As[cb][(unsigned)m * 32 + foff];
        }
#pragma unroll
        for (int j = 0; j < 4; ++j) {
            int n = n_w + j * 16 + lrow;
            bfr[j] = *(const bf16x8*)&Bs[cb][(unsigned)n * 32 + foff];
        }
#pragma unroll
        for (int i = 0; i < 4; ++i)
#pragma unroll
            for (int j = 0; j < 4; ++j)
                acc[i][j] = __builtin_amdgcn_mfma_f32_16x16x32_bf16(af[i], bfr[j], acc[i][j], 0, 0, 0);
    }
    asm volatile("s_waitcnt vmcnt(0)" ::: "memory");

    const float* bias = b2 + (size_t)e * HH + (size_t)nt * 128;
    bf16* Yb = Y + ((size_t)ks * ROWS_CAP + row0) * HH + (size_t)nt * 128;
#pragma unroll
    for (int j = 0; j < 4; ++j) {
        int col = n_w + j * 16 + lrow;
        float bv = (ks == 0) ? bias[col] : 0.f;
#pragma unroll
        for (int i = 0; i < 4; ++i)
#pragma unroll
            for (int r = 0; r < 4; ++r) {
                int mrow = m_w + i * 16 + (lq << 2) + r;
                bf16 bvv = (bf16)(acc[i][j][r] + bv);
                unsigned short u;
                __builtin_memcpy(&u, &bvv, 2);
                // NT store: Y is write-once-read-later; don't evict weights from L3
                __builtin_nontemporal_store(u, (unsigned short*)&Yb[(size_t)mrow * HH + col]);
            }
    }
}

// ---- combine: out[t] = sum_slot w_slot * sum_ks y[ks][row_slot] ----
__global__ __launch_bounds__(256) void combine_kernel(const bf16* __restrict__ Y,
                                                      const int* __restrict__ rowOf,
                                                      const float* __restrict__ tkw,
                                                      float* __restrict__ out) {
    const int t = blockIdx.x;
    const int tid = threadIdx.x;
    const int ra = rowOf[t * 2 + 0], rb = rowOf[t * 2 + 1];
    const float wa = tkw[t * 2 + 0], wb = tkw[t * 2 + 1];
    const int c = tid * 4;
    float acc[4] = {0.f, 0.f, 0.f, 0.f};
#pragma unroll
    for (int ks = 0; ks < KSPLIT2; ++ks) {
        bf16x4 a = *(const bf16x4*)&Y[((size_t)ks * ROWS_CAP + ra) * HH + c];
        bf16x4 b = *(const bf16x4*)&Y[((size_t)ks * ROWS_CAP + rb) * HH + c];
#pragma unroll
        for (int k = 0; k < 4; ++k) acc[k] += wa * (float)a[k] + wb * (float)b[k];
    }
    floatx4 o; o[0] = acc[0]; o[1] = acc[1]; o[2] = acc[2]; o[3] = acc[3];
    *(floatx4*)&out[(size_t)t * HH + c] = o;
}

extern "C" void kernel_launch(void* const* d_in, const int* in_sizes, int n_in,
                              void* d_out, int out_size, void* d_ws, size_t ws_size,
                              hipStream_t stream) {
    const float* x  = (const float*)d_in[0];
    const float* gw = (const float*)d_in[1];
    const float* gb = (const float*)d_in[2];
    const float* w1 = (const float*)d_in[3];
    const float* b1 = (const float*)d_in[4];
    const float* w2 = (const float*)d_in[5];
    const float* b2 = (const float*)d_in[6];
    float* out = (float*)d_out;
    char* ws = (char*)d_ws;

    bf16*  w1t  = (bf16*)(ws + OFF_W1T);
    bf16*  w2t  = (bf16*)(ws + OFF_W2T);
    bf16*  xg   = (bf16*)(ws + OFF_XG);
    bf16*  hbuf = (bf16*)(ws + OFF_H);
    bf16*  ybuf = (bf16*)(ws + OFF_Y);     // aliases w1t (dead after gemm1)
    int*   cnts = (int*)(ws + OFF_CNT);
    int*   ofs  = (int*)(ws + OFF_OFS);
    int*   tke  = (int*)(ws + OFF_TKE);
    int*   tkr  = (int*)(ws + OFF_TKR);
    float* tkw  = (float*)(ws + OFF_TKW);
    int*   rowOf= (int*)(ws + OFF_ROW);

    hipMemsetAsync(cnts, 0, 256, stream);
    hipMemsetAsync(xg, 0, (size_t)ROWS_CAP * HH * sizeof(bf16), stream);

    transpose_cvt<<<dim3(FF / 64, HH / 64, EE), 256, 0, stream>>>(w1, w1t, HH, FF);
    transpose_cvt<<<dim3(HH / 64, FF / 64, EE), 256, 0, stream>>>(w2, w2t, FF, HH);
    router_kernel<<<128, 256, 0, stream>>>(x, gw, gb, cnts, tke, tkr, tkw);
    scan_offsets<<<1, 64, 0, stream>>>(cnts, ofs);
    gather_kernel<<<TT * 2, 256, 0, stream>>>(x, tke, tkr, ofs, xg, rowOf);
    gemm1_kernel<<<dim3(FF / 128, 16, EE), 256, 0, stream>>>(xg, w1t, b1, hbuf, cnts, ofs);
    gemm2_kernel<<<dim3(HH / 128, 16, EE * KSPLIT2), 256, 0, stream>>>(hbuf, w2t, b2, ybuf, cnts, ofs);
    combine_kernel<<<TT, 256, 0, stream>>>(ybuf, rowOf, tkw, out);
}

// Round 4
// 510.154 us; speedup vs baseline: 1.1049x; 1.0047x over previous
//
#include <hip/hip_runtime.h>

// ---- problem dims (fixed) ----
#define TT 2048   // tokens = B*S
#define HH 1024   // hidden
#define FF 4096   // intermediate
#define EE 8      // experts
#define ROWS_CAP 5120  // 4096 token-slots + per-expert pad to 128, rounded up
#define KSPLIT2 4      // gemm2 split-K factor

typedef __bf16 bf16;
typedef bf16 bf16x8 __attribute__((ext_vector_type(8)));
typedef bf16 bf16x4 __attribute__((ext_vector_type(4)));
typedef bf16 bf16x2 __attribute__((ext_vector_type(2)));
typedef float floatx4 __attribute__((ext_vector_type(4)));

// ---- workspace layout (bytes) ----
#define OFF_W1T  ((size_t)0)                       // [E][F][H] bf16 = 67108864
#define OFF_W2T  (OFF_W1T + (size_t)67108864)      // [E][H][F] bf16 = 67108864
#define OFF_XG   (OFF_W2T + (size_t)67108864)      // [ROWS_CAP][H] bf16 = 10485760
#define OFF_H    (OFF_XG  + (size_t)10485760)      // [ROWS_CAP][F] bf16 = 41943040
#define OFF_CNT  (OFF_H   + (size_t)41943040)      // int[8] (256B slot)
#define OFF_OFS  (OFF_CNT + (size_t)256)           // int[8] (256B slot)
#define OFF_TKE  (OFF_OFS + (size_t)256)           // int[T][2]
#define OFF_TKR  (OFF_TKE + (size_t)16384)         // int[T][2]
#define OFF_TKW  (OFF_TKR + (size_t)16384)         // float[T][2]
#define OFF_ROW  (OFF_TKW + (size_t)16384)         // int[T][2] row index per (token,slot)
// Y partials [KSPLIT2][ROWS_CAP][HH] bf16 = 41943040 bytes — ALIASES w1t region:
// w1t is dead after gemm1 (stream order: transpose -> gemm1 -> gemm2 -> combine).
#define OFF_Y    OFF_W1T

// async global->LDS, 16B per lane; LDS dest is wave-uniform base + lane*16
__device__ __forceinline__ void gload16(const bf16* g, bf16* l) {
    __builtin_amdgcn_global_load_lds((const __attribute__((address_space(1))) void*)g,
                                     (__attribute__((address_space(3))) void*)l, 16, 0, 0);
}

// raw workgroup barrier WITHOUT the __syncthreads() vmcnt(0) drain —
// execution sync only; we manage vmcnt ourselves (m139 technique).
__device__ __forceinline__ void raw_barrier() {
    asm volatile("s_barrier" ::: "memory");
}

// ---- transpose + fp32->bf16 convert: in[e][r][c] fp32 -> out[e][c][r] bf16 ----
__global__ __launch_bounds__(256) void transpose_cvt(const float* __restrict__ in,
                                                     bf16* __restrict__ out,
                                                     int R, int C) {
    __shared__ float tile[64][67];
    const int e  = blockIdx.z;
    const int r0 = blockIdx.y * 64, c0 = blockIdx.x * 64;
    const float* inp = in + (size_t)e * R * C;
    bf16* outp = out + (size_t)e * R * C;
    const int t = threadIdx.x;
    {
        const int lr = t >> 4;            // 0..15
        const int lc = (t & 15) << 2;     // 0..60 step 4
#pragma unroll
        for (int i = 0; i < 4; ++i) {
            int r = lr + i * 16;
            floatx4 v = __builtin_nontemporal_load(
                (const floatx4*)&inp[(size_t)(r0 + r) * C + c0 + lc]);
            tile[r][lc + 0] = v[0]; tile[r][lc + 1] = v[1];
            tile[r][lc + 2] = v[2]; tile[r][lc + 3] = v[3];
        }
    }
    __syncthreads();
    {
        const int c  = t >> 3;            // 0..31
        const int rq = (t & 7) << 3;      // 0..56 step 8
#pragma unroll
        for (int i = 0; i < 2; ++i) {
            int cc = c + i * 32;
            bf16x8 o;
#pragma unroll
            for (int k = 0; k < 8; ++k) o[k] = (bf16)tile[rq + k][cc];
            *(bf16x8*)&outp[(size_t)(c0 + cc) * R + r0 + rq] = o;
        }
    }
}

// ---- router: fp64-accurate logits, top-2, renormalized weights, rank via atomics ----
__global__ __launch_bounds__(256) void router_kernel(const float* __restrict__ x,
                                                     const float* __restrict__ gw,
                                                     const float* __restrict__ gb,
                                                     int* __restrict__ counts,
                                                     int* __restrict__ tke,
                                                     int* __restrict__ tkr,
                                                     float* __restrict__ tkw) {
    const int wave = blockIdx.x * 4 + (threadIdx.x >> 6);
    const int lane = threadIdx.x & 63;
    const int nw = gridDim.x * 4;
    for (int t = wave; t < TT; t += nw) {
        const float* xr = x + (size_t)t * HH;
        double acc[EE];
#pragma unroll
        for (int e = 0; e < EE; ++e) acc[e] = 0.0;
        for (int h = lane; h < HH; h += 64) {
            double xv = (double)xr[h];
            const float* g = gw + (size_t)h * EE;
            floatx4 g0 = *(const floatx4*)&g[0];
            floatx4 g1 = *(const floatx4*)&g[4];
            acc[0] += xv * (double)g0[0]; acc[1] += xv * (double)g0[1];
            acc[2] += xv * (double)g0[2]; acc[3] += xv * (double)g0[3];
            acc[4] += xv * (double)g1[0]; acc[5] += xv * (double)g1[1];
            acc[6] += xv * (double)g1[2]; acc[7] += xv * (double)g1[3];
        }
#pragma unroll
        for (int e = 0; e < EE; ++e) {
            double v = acc[e];
            for (int s = 32; s > 0; s >>= 1) v += __shfl_xor(v, s, 64);
            acc[e] = v + (double)gb[e];
        }
        if (lane == 0) {
            int i1 = 0; double v1 = acc[0];
            for (int e = 1; e < EE; ++e) if (acc[e] > v1) { v1 = acc[e]; i1 = e; }
            int i2 = -1; double v2 = -1e300;
            for (int e = 0; e < EE; ++e) if (e != i1 && acc[e] > v2) { v2 = acc[e]; i2 = e; }
            double wa = 1.0 / (1.0 + exp(v2 - v1));   // = renormalized softmax of top-2
            double wb = 1.0 - wa;
            int r1 = atomicAdd(&counts[i1], 1);
            int r2 = atomicAdd(&counts[i2], 1);
            tke[t * 2 + 0] = i1; tke[t * 2 + 1] = i2;
            tkr[t * 2 + 0] = r1; tkr[t * 2 + 1] = r2;
            tkw[t * 2 + 0] = (float)wa; tkw[t * 2 + 1] = (float)wb;
        }
    }
}

// ---- exclusive scan of counts padded to 128 ----
__global__ void scan_offsets(const int* __restrict__ counts, int* __restrict__ offs) {
    if (threadIdx.x == 0 && blockIdx.x == 0) {
        int off = 0;
        for (int e = 0; e < EE; ++e) {
            offs[e] = off;
            off += (counts[e] + 127) & ~127;
        }
    }
}

// ---- gather token rows into expert-grouped bf16 matrix; record row per (token,slot) ----
// NOTE: pad rows keep harness 0xAA poison = tiny finite bf16 — pad outputs never combined.
__global__ __launch_bounds__(256) void gather_kernel(const float* __restrict__ x,
                                                     const int* __restrict__ tke,
                                                     const int* __restrict__ tkr,
                                                     const int* __restrict__ offs,
                                                     bf16* __restrict__ xg,
                                                     int* __restrict__ rowOf) {
    const int pair = blockIdx.x;       // t*2 + slot
    const int t = pair >> 1;
    const int e = tke[pair];
    const int row = offs[e] + tkr[pair];
    const float* xr = x + (size_t)t * HH;
    bf16* dst = xg + (size_t)row * HH;
    const int tid = threadIdx.x;
    floatx4 v = ((const floatx4*)xr)[tid];
    bf16x4 o;
    o[0] = (bf16)v[0]; o[1] = (bf16)v[1]; o[2] = (bf16)v[2]; o[3] = (bf16)v[3];
    ((bf16x4*)dst)[tid] = o;
    if (tid == 0) rowOf[pair] = row;
}

// ================= GEMM core: 128M x 256N x 32K tile, 3-stage LDS pipeline =================
// A: [M][K] bf16 (row-major, K contiguous). Bt: [N][K] bf16. 256 threads, 4 waves (2Mx2N).
// Prefetch distance 2: 18 loads in flight, wait vmcnt(12) for the current tile only.
// Raw s_barrier (no vmcnt drain). LDS: 3*(8KB A + 16KB B) = 72 KB -> 2 blocks/CU.

#define GEMM_BODY(EPILOGUE)                                                                 \
    __shared__ bf16 As[3][128 * 32];                                                        \
    __shared__ bf16 Bs[3][256 * 32];                                                        \
    const int tid = threadIdx.x;                                                            \
    const int lane = tid & 63, wave = tid >> 6;                                             \
    const int lrow = lane & 15, lq = lane >> 4;                                             \
    const int m_w = (wave & 1) << 6, n_w = (wave >> 1) << 7;                                \
    const unsigned foff = (unsigned)((lq ^ ((lrow >> 1) & 3)) << 3);                        \
    floatx4 acc[4][8];                                                                      \
    _Pragma("unroll") for (int i = 0; i < 4; ++i)                                           \
        _Pragma("unroll") for (int j = 0; j < 8; ++j)                                       \
            acc[i][j] = (floatx4){0.f, 0.f, 0.f, 0.f};                                      \
    int arow[6]; size_t gadr[6];                                                            \
    _Pragma("unroll") for (int s = 0; s < 6; ++s) {                                         \
        int c = tid + ((s < 2) ? s * 256 : (s - 2) * 256);                                  \
        int ar = c >> 2, ak = (c & 3) ^ ((ar >> 1) & 3);                                    \
        arow[s] = ar; gadr[s] = (size_t)ar * K + (size_t)ak * 8;                            \
    }                                                                                       \
    const unsigned ldsw = (unsigned)((tid & ~63) << 4); /* wave*1024 bytes */               \
    /* prologue: tiles 0 and 1 */                                                           \
    _Pragma("unroll") for (int p = 0; p < 2; ++p) {                                         \
        const int kb = p * 32;                                                              \
        gload16(Ab + gadr[0] + kb, (bf16*)((char*)As[p] + ldsw));                           \
        gload16(Ab + gadr[1] + kb, (bf16*)((char*)As[p] + 4096u + ldsw));                   \
        gload16(Bb + gadr[2] + kb, (bf16*)((char*)Bs[p] + ldsw));                           \
        gload16(Bb + gadr[3] + kb, (bf16*)((char*)Bs[p] + 4096u + ldsw));                   \
        gload16(Bb + gadr[4] + kb, (bf16*)((char*)Bs[p] + 8192u + ldsw));                   \
        gload16(Bb + gadr[5] + kb, (bf16*)((char*)Bs[p] + 12288u + ldsw));                  \
    }                                                                                       \
    for (int kt = 0; kt < NK; ++kt) {                                                       \
        raw_barrier();             /* all waves done computing tile kt-1 */                 \
        {                                                                                   \
            const int kn = (kt + 2 < NK) ? kt + 2 : NK - 1;  /* clamp: uniform vmcnt */     \
            const int nb = (kt + 2) % 3;                                                    \
            const int kb = kn * 32;                                                         \
            gload16(Ab + gadr[0] + kb, (bf16*)((char*)As[nb] + ldsw));                      \
            gload16(Ab + gadr[1] + kb, (bf16*)((char*)As[nb] + 4096u + ldsw));              \
            gload16(Bb + gadr[2] + kb, (bf16*)((char*)Bs[nb] + ldsw));                      \
            gload16(Bb + gadr[3] + kb, (bf16*)((char*)Bs[nb] + 4096u + ldsw));              \
            gload16(Bb + gadr[4] + kb, (bf16*)((char*)Bs[nb] + 8192u + ldsw));              \
            gload16(Bb + gadr[5] + kb, (bf16*)((char*)Bs[nb] + 12288u + ldsw));             \
        }                                                                                   \
        asm volatile("s_waitcnt vmcnt(12)" ::: "memory"); /* my tile-kt loads landed */     \
        raw_barrier();                                    /* everyone's landed */           \
        const int cb = kt % 3;                                                              \
        bf16x8 af[4], bfr[8];                                                               \
        _Pragma("unroll") for (int i = 0; i < 4; ++i) {                                     \
            int m = m_w + i * 16 + lrow;                                                    \
            af[i] = *(const bf16x8*)&As[cb][(unsigned)m * 32 + foff];                       \
        }                                                                                   \
        _Pragma("unroll") for (int j = 0; j < 8; ++j) {                                     \
            int n = n_w + j * 16 + lrow;                                                    \
            bfr[j] = *(const bf16x8*)&Bs[cb][(unsigned)n * 32 + foff];                      \
        }                                                                                   \
        _Pragma("unroll") for (int i = 0; i < 4; ++i)                                       \
            _Pragma("unroll") for (int j = 0; j < 8; ++j)                                   \
                acc[i][j] = __builtin_amdgcn_mfma_f32_16x16x32_bf16(af[i], bfr[j],          \
                                                                    acc[i][j], 0, 0, 0);    \
    }                                                                                       \
    asm volatile("s_waitcnt vmcnt(0)" ::: "memory"); /* drain DMA before endpgm */          \
    EPILOGUE

// ---- GEMM1: h = relu(xg @ w1[e] + b1[e]) -> bf16 ----
__global__ __launch_bounds__(256, 2) void gemm1_kernel(const bf16* __restrict__ A,
                                                       const bf16* __restrict__ Bt,
                                                       const float* __restrict__ b1,
                                                       bf16* __restrict__ Hout,
                                                       const int* __restrict__ counts,
                                                       const int* __restrict__ offs) {
    const int e = blockIdx.z, mt = blockIdx.y, nt = blockIdx.x;
    const int cnt = counts[e];
    if (mt * 128 >= cnt) return;
    const int row0 = offs[e] + mt * 128;
    const int K = HH;
    const int NK = K / 32;
    const bf16* Ab = A + (size_t)row0 * K;
    const bf16* Bb = Bt + ((size_t)e * FF + (size_t)nt * 256) * K;

    GEMM_BODY({
        const float* bias = b1 + (size_t)e * FF + (size_t)nt * 256;
        bf16* Hb = Hout + (size_t)row0 * FF + (size_t)nt * 256;
        _Pragma("unroll") for (int j = 0; j < 8; ++j) {
            int col = n_w + j * 16 + lrow;
            float bv = bias[col];
            _Pragma("unroll") for (int i = 0; i < 4; ++i)
                _Pragma("unroll") for (int r = 0; r < 4; ++r) {
                    int mrow = m_w + i * 16 + (lq << 2) + r;  // C/D: col=lane&15, row=quad*4+reg
                    float v = acc[i][j][r] + bv;
                    Hb[(size_t)mrow * FF + col] = (bf16)(v > 0.f ? v : 0.f);
                }
        }
    })
}

// ---- GEMM2: y[ks][row] = h-slice @ w2-slice (+b2 at ks==0) -> bf16, plain stores ----
__global__ __launch_bounds__(256, 2) void gemm2_kernel(const bf16* __restrict__ Hin,
                                                       const bf16* __restrict__ Bt,
                                                       const float* __restrict__ b2,
                                                       bf16* __restrict__ Y,
                                                       const int* __restrict__ counts,
                                                       const int* __restrict__ offs) {
    const int e = blockIdx.z >> 2, ks = blockIdx.z & 3;
    const int mt = blockIdx.y, nt = blockIdx.x;
    const int cnt = counts[e];
    if (mt * 128 >= cnt) return;
    const int row0 = offs[e] + mt * 128;
    const int K = FF;                      // full-K row stride
    const int KC = FF / KSPLIT2;           // 1024 per split
    const int NK = KC / 32;
    const bf16* Ab = Hin + (size_t)row0 * K + ks * KC;
    const bf16* Bb = Bt + ((size_t)e * HH + (size_t)nt * 256) * K + ks * KC;

    GEMM_BODY({
        const float* bias = b2 + (size_t)e * HH + (size_t)nt * 256;
        bf16* Yb = Y + ((size_t)ks * ROWS_CAP + row0) * HH + (size_t)nt * 256;
        _Pragma("unroll") for (int j = 0; j < 8; ++j) {
            int col = n_w + j * 16 + lrow;
            float bv = (ks == 0) ? bias[col] : 0.f;
            _Pragma("unroll") for (int i = 0; i < 4; ++i)
                _Pragma("unroll") for (int r = 0; r < 4; ++r) {
                    int mrow = m_w + i * 16 + (lq << 2) + r;
                    Yb[(size_t)mrow * HH + col] = (bf16)(acc[i][j][r] + bv);
                }
        }
    })
}

// ---- combine: out[t] = sum_slot w_slot * sum_ks y[ks][row_slot] ----
__global__ __launch_bounds__(256) void combine_kernel(const bf16* __restrict__ Y,
                                                      const int* __restrict__ rowOf,
                                                      const float* __restrict__ tkw,
                                                      float* __restrict__ out) {
    const int t = blockIdx.x;
    const int tid = threadIdx.x;
    const int ra = rowOf[t * 2 + 0], rb = rowOf[t * 2 + 1];
    const float wa = tkw[t * 2 + 0], wb = tkw[t * 2 + 1];
    const int c = tid * 4;
    float acc[4] = {0.f, 0.f, 0.f, 0.f};
#pragma unroll
    for (int ks = 0; ks < KSPLIT2; ++ks) {
        bf16x4 a = *(const bf16x4*)&Y[((size_t)ks * ROWS_CAP + ra) * HH + c];
        bf16x4 b = *(const bf16x4*)&Y[((size_t)ks * ROWS_CAP + rb) * HH + c];
#pragma unroll
        for (int k = 0; k < 4; ++k) acc[k] += wa * (float)a[k] + wb * (float)b[k];
    }
    floatx4 o; o[0] = acc[0]; o[1] = acc[1]; o[2] = acc[2]; o[3] = acc[3];
    *(floatx4*)&out[(size_t)t * HH + c] = o;
}

extern "C" void kernel_launch(void* const* d_in, const int* in_sizes, int n_in,
                              void* d_out, int out_size, void* d_ws, size_t ws_size,
                              hipStream_t stream) {
    const float* x  = (const float*)d_in[0];
    const float* gw = (const float*)d_in[1];
    const float* gb = (const float*)d_in[2];
    const float* w1 = (const float*)d_in[3];
    const float* b1 = (const float*)d_in[4];
    const float* w2 = (const float*)d_in[5];
    const float* b2 = (const float*)d_in[6];
    float* out = (float*)d_out;
    char* ws = (char*)d_ws;

    bf16*  w1t  = (bf16*)(ws + OFF_W1T);
    bf16*  w2t  = (bf16*)(ws + OFF_W2T);
    bf16*  xg   = (bf16*)(ws + OFF_XG);
    bf16*  hbuf = (bf16*)(ws + OFF_H);
    bf16*  ybuf = (bf16*)(ws + OFF_Y);     // aliases w1t (dead after gemm1)
    int*   cnts = (int*)(ws + OFF_CNT);
    int*   ofs  = (int*)(ws + OFF_OFS);
    int*   tke  = (int*)(ws + OFF_TKE);
    int*   tkr  = (int*)(ws + OFF_TKR);
    float* tkw  = (float*)(ws + OFF_TKW);
    int*   rowOf= (int*)(ws + OFF_ROW);

    hipMemsetAsync(cnts, 0, 256, stream);

    transpose_cvt<<<dim3(FF / 64, HH / 64, EE), 256, 0, stream>>>(w1, w1t, HH, FF);
    transpose_cvt<<<dim3(HH / 64, FF / 64, EE), 256, 0, stream>>>(w2, w2t, FF, HH);
    router_kernel<<<128, 256, 0, stream>>>(x, gw, gb, cnts, tke, tkr, tkw);
    scan_offsets<<<1, 64, 0, stream>>>(cnts, ofs);
    gather_kernel<<<TT * 2, 256, 0, stream>>>(x, tke, tkr, ofs, xg, rowOf);
    gemm1_kernel<<<dim3(FF / 256, 16, EE), 256, 0, stream>>>(xg, w1t, b1, hbuf, cnts, ofs);
    gemm2_kernel<<<dim3(HH / 256, 16, EE * KSPLIT2), 256, 0, stream>>>(hbuf, w2t, b2, ybuf, cnts, ofs);
    combine_kernel<<<TT, 256, 0, stream>>>(ybuf, rowOf, tkw, out);
}